// Round 12
// baseline (402.327 us; speedup 1.0000x reference)
//
#include <hip/hip_runtime.h>
#include <hip/hip_bf16.h>

#define NN 50000      // nodes
#define NE 800000     // edges
#define NR 20         // relations
#define NB 8          // bases
#define D  128        // hidden dim
#define DO 64         // output dim
#define NT 782        // ceil(NN/64) dst tiles (bucket space granularity)
#define NST 3125      // NN/16 subtiles (k_mega grid) -- exact
#define NBKT (NT*1280) // (tile, rel, dl) buckets = 1,000,960
#define NSB 978       // ceil(NBKT/1024)

typedef __attribute__((ext_vector_type(8))) short short8;
typedef __attribute__((ext_vector_type(4))) float f32x4;

__device__ inline unsigned short f2bf(float f) {
    __hip_bfloat16 h = __float2bfloat16(f);
    return *reinterpret_cast<unsigned short*>(&h);
}
__device__ inline float bf2f(unsigned short u) {
    unsigned x = ((unsigned)u) << 16;
    float f;
    __builtin_memcpy(&f, &x, 4);
    return f;
}

// ---------------------------------------------------------------------------
// ws layout (bytes):
//   [0        ..  4,003,840) cnt2  | [4,003,840.. 4,007,752) bsum
//   [4,007,808..  8,011,652) boff2 | [8,011,712..12,015,552) gcur2
//   [12,015,616..12,025,856) W0    | [12,025,856..12,681,216) W1b
//   [12,681,216..25,481,216) h1b   | [25,481,216..28,681,216) epack
//   [28,681,216..28,697,600) linWb (lin_w in B-fragment order, bf16)
// ---------------------------------------------------------------------------

__global__ __launch_bounds__(256) void k_weights(
        const float* __restrict__ basis0, const float* __restrict__ wcomp0,
        const float* __restrict__ basis1, const float* __restrict__ wcomp1,
        const float* __restrict__ lin_w,
        float* __restrict__ W0, unsigned short* __restrict__ W1b,
        unsigned short* __restrict__ linWb) {
    int idx = blockIdx.x * 256 + threadIdx.x;   // 0..40959
    if (idx < NR * D) {
        int r = idx / D, o = idx % D;
        float a = 0.f;
        #pragma unroll
        for (int b = 0; b < NB; b++) a += wcomp0[r * NB + b] * basis0[b * D + o];
        W0[idx] = a;
    }
    if (idx < 16 * 64) {
        int lane = idx & 63, fr = idx >> 6;
        int kc = fr >> 2, nt = fr & 3;
        int i0 = kc * 32 + (lane >> 4) * 8;
        int o = nt * 16 + (lane & 15);
        short8 v;
        #pragma unroll
        for (int e = 0; e < 8; e++) v[e] = (short)f2bf(lin_w[(i0 + e) * DO + o]);
        *((short8*)linWb + idx) = v;
    }
    if (idx < NR * 4 * 8 * 64) {
        int lane = idx & 63;
        int cb   = (idx >> 6) & 7;
        int kc   = (idx >> 9) & 3;
        int rel  = idx >> 11;
        float wc[NB];
        #pragma unroll
        for (int b = 0; b < NB; b++) wc[b] = wcomp1[rel * NB + b];
        int o  = cb * 16 + (lane & 15);
        int i0 = kc * 32 + (lane >> 4) * 8;
        short8 v;
        #pragma unroll
        for (int e = 0; e < 8; e++) {
            int i = i0 + e;
            float a = 0.f;
            #pragma unroll
            for (int b = 0; b < NB; b++) a += wc[b] * basis1[(b * D + i) * D + o];
            v[e] = (short)f2bf(a);
        }
        *((short8*)W1b + idx) = v;
    }
}

__global__ __launch_bounds__(1024) void k_hist(
        const int* __restrict__ dst, const int* __restrict__ et,
        int* __restrict__ cnt2) {
    int i = blockIdx.x * 1024 + threadIdx.x;
    if (i < NE) {
        int d = dst[i];
        int key = (d >> 6) * 1280 + et[i] * 64 + (d & 63);
        atomicAdd(&cnt2[key], 1);
    }
}

__global__ __launch_bounds__(1024) void k_scan1(const int* __restrict__ cnt2,
                                                int* __restrict__ boff2,
                                                int* __restrict__ bsum) {
    __shared__ int ws[16];
    int t = threadIdx.x, lane = t & 63, wv = t >> 6;
    int i = blockIdx.x * 1024 + t;
    int v = (i < NBKT) ? cnt2[i] : 0;
    int inc = v;
    for (int dd = 1; dd < 64; dd <<= 1) {
        int u = __shfl_up(inc, dd);
        if (lane >= dd) inc += u;
    }
    if (lane == 63) ws[wv] = inc;
    __syncthreads();
    if (t == 0) { int a = 0; for (int j = 0; j < 16; j++) { int x = ws[j]; ws[j] = a; a += x; } }
    __syncthreads();
    int ex = ws[wv] + inc - v;
    if (i < NBKT) boff2[i] = ex;
    if (t == 1023) bsum[blockIdx.x] = ex + v;
}

__global__ __launch_bounds__(1024) void k_scan2(int* __restrict__ bsum) {
    __shared__ int ws[16];
    int t = threadIdx.x, lane = t & 63, wv = t >> 6;
    int v = (t < NSB) ? bsum[t] : 0;
    int inc = v;
    for (int dd = 1; dd < 64; dd <<= 1) {
        int u = __shfl_up(inc, dd);
        if (lane >= dd) inc += u;
    }
    if (lane == 63) ws[wv] = inc;
    __syncthreads();
    if (t == 0) { int a = 0; for (int j = 0; j < 16; j++) { int x = ws[j]; ws[j] = a; a += x; } }
    __syncthreads();
    if (t < NSB) bsum[t] = ws[wv] + inc - v;
}

__global__ __launch_bounds__(1024) void k_scan3(int* __restrict__ boff2,
                                                const int* __restrict__ bsum,
                                                int* __restrict__ gcur2) {
    int i = blockIdx.x * 1024 + threadIdx.x;
    if (i < NBKT) {
        int f = boff2[i] + bsum[i >> 10];
        boff2[i] = f;
        gcur2[i] = f;
    }
    if (i == 0) boff2[NBKT] = NE;
}

__global__ __launch_bounds__(1024) void k_scatter(
        const int* __restrict__ src, const int* __restrict__ dst,
        const int* __restrict__ et, int* __restrict__ gcur2,
        int* __restrict__ epack) {
    int i = blockIdx.x * 1024 + threadIdx.x;
    if (i < NE) {
        int d = dst[i];
        int key = (d >> 6) * 1280 + et[i] * 64 + (d & 63);
        int pos = atomicAdd(&gcur2[key], 1);
        epack[pos] = src[i];
    }
}

__global__ __launch_bounds__(512) void k_h1(const int* __restrict__ cnt2,
                                            const float* __restrict__ W0,
                                            const float* __restrict__ bias0,
                                            unsigned short* __restrict__ h1b) {
    __shared__ float cs[NR * 64];
    __shared__ float w0s[NR * D];
    int t = threadIdx.x, tile = blockIdx.x;
    for (int i = t; i < NR * 64; i += 512) cs[i] = (float)cnt2[tile * 1280 + i];
    for (int i = t; i < NR * D; i += 512) w0s[i] = W0[i];
    __syncthreads();
    int nl = t >> 3, cg = t & 7;
    int n = tile * 64 + nl;
    if (n < NN) {
        float a[16];
        #pragma unroll
        for (int j = 0; j < 16; j++) a[j] = bias0[cg * 16 + j];
        for (int r = 0; r < NR; r++) {
            float c = cs[r * 64 + nl];
            #pragma unroll
            for (int j = 0; j < 16; j++) a[j] += c * w0s[r * D + cg * 16 + j];
        }
        short8 o0, o1;
        #pragma unroll
        for (int j = 0; j < 8; j++) {
            o0[j] = (short)f2bf(fmaxf(a[j], 0.f));
            o1[j] = (short)f2bf(fmaxf(a[8 + j], 0.f));
        }
        *((short8*)(h1b + n * D + cg * 16))     = o0;
        *((short8*)(h1b + n * D + cg * 16 + 8)) = o1;
    }
}

// Mega v10: one 256-thr block per 16-dst subtile; 4 waves K-split (wave wv owns
// h1 cols / W1 rows wv*32..wv*32+31), zero barriers in the main loop.
// Block prologue stages edge ids (epk ushort) + bucket offsets in LDS.
// Per-wave flat chunk stream (<=16 edges/chunk) with DEPTH-2 register
// prefetch of the 64B quarter-row gather; reduce from a double-buffered
// wave-private Raw slice; A-fragment is the reduce output directly (the old
// Sl publish/read was an identity). 8 MFMA per rel, B from L2-resident W1b.
// Merge: LDS atomicAdd into 8KB agg; epilogue linear 128->64 via MFMA.
__global__ __launch_bounds__(256, 4) void k_mega(
        const int* __restrict__ epack, const int* __restrict__ boff2,
        const unsigned short* __restrict__ h1b,
        const unsigned short* __restrict__ W1b,
        const unsigned short* __restrict__ linWb,
        const float* __restrict__ bias1, const float* __restrict__ lin_b,
        float* __restrict__ out) {
    __shared__ __align__(16) char slices[4 * 2560];   // per-wave Raw dbuf; Af alias
    __shared__ __align__(16) float aggf[2048];        // 8 KB merge buffer
    __shared__ int rawoff[341];                       // abs bucket offsets (17/rel)
    __shared__ int sofs[21];                          // compact epk rel starts
    __shared__ unsigned short ct[96];                 // chunk table (r<<3)|c
    __shared__ unsigned short epk[512];               // subtile edge src ids
    __shared__ int nchS;

    int t = threadIdx.x, st = blockIdx.x;
    int wv = t >> 6, lane = t & 63;
    int tile = st >> 2, q = st & 3;
    int dl = lane & 15, half = lane >> 4;    // reduce/mfma roles
    int se = lane >> 2, pp = lane & 3;       // stage roles: edge, 16B part

    int kb = tile * 1280 + q * 16;
    for (int i = t; i < 340; i += 256) {
        int r = i / 17, j = i - r * 17;
        rawoff[i] = boff2[kb + r * 64 + j];
    }
    for (int i = t; i < 2048; i += 256) aggf[i] = 0.f;
    __syncthreads();
    if (t == 0) {
        int a = 0;
        for (int r = 0; r < NR; r++) {
            sofs[r] = a;
            a += rawoff[r * 17 + 16] - rawoff[r * 17];
        }
        sofs[NR] = a;
    }
    if (t == 64) {
        int j = 0;
        for (int r = 0; r < NR; r++) {
            int cnt = rawoff[r * 17 + 16] - rawoff[r * 17];
            int ncc = (cnt + 15) >> 4;
            for (int c = 0; c < ncc && j < 96; c++) ct[j++] = (unsigned short)((r << 3) | c);
        }
        nchS = j;
    }
    __syncthreads();
    // stage subtile's edge ids (compact, per-rel contiguous)
    for (int r = 0; r < NR; r++) {
        int g0 = rawoff[r * 17];
        int cnt = rawoff[r * 17 + 16] - g0;
        int s0 = sofs[r];
        for (int j = t; j < cnt; j += 256)
            if (s0 + j < 512) epk[s0 + j] = (unsigned short)epack[g0 + j];
    }
    __syncthreads();

    short8* Raw8 = (short8*)(slices + wv * 2560);     // [2 bufs][16 rows][5 pad]

    f32x4 acc[8];
    #pragma unroll
    for (int j = 0; j < 8; j++) acc[j] = (f32x4){0.f, 0.f, 0.f, 0.f};
    float s[8];
    #pragma unroll
    for (int k = 0; k < 8; k++) s[k] = 0.f;

    int nch = nchS;
    short8 v = {0,0,0,0,0,0,0,0}, vN = v;
    int m = 0, mN = 0, buf = 0;

    // issue chunk 0
    if (nch > 0) {
        int e = ct[0]; int r = e >> 3, c = e & 7;
        int g0 = rawoff[r * 17];
        int cnt = rawoff[r * 17 + 16] - g0;
        m = min(16, cnt - c * 16);
        if (se < m) {
            int node = epk[sofs[r] + c * 16 + se];
            v = *((const short8*)(h1b + (size_t)node * D) + wv * 4 + pp);
        }
    }

    for (int j = 0; j < nch; j++) {
        int e = ct[j]; int r = e >> 3, c = e & 7;
        int g0 = rawoff[r * 17];
        int cnt = rawoff[r * 17 + 16] - g0;
        bool lastofrel = ((c + 1) * 16 >= cnt);
        // issue chunk j+1 (gather in flight during this chunk's work)
        if (j + 1 < nch) {
            int e2 = ct[j + 1]; int r2 = e2 >> 3, c2 = e2 & 7;
            int g02 = rawoff[r2 * 17];
            int cnt2v = rawoff[r2 * 17 + 16] - g02;
            mN = min(16, cnt2v - c2 * 16);
            if (se < mN) {
                int node = epk[sofs[r2] + c2 * 16 + se];
                vN = *((const short8*)(h1b + (size_t)node * D) + wv * 4 + pp);
            }
        } else mN = 0;
        // write chunk j to Raw[buf] (vmcnt wait allows vN to stay in flight)
        if (se < m) Raw8[buf * 80 + se * 5 + pp] = v;
        asm volatile("s_waitcnt lgkmcnt(0)" ::: "memory");
        // reduce own bucket's rows of this chunk
        {
            int b0 = rawoff[r * 17 + dl] - g0;
            int b1 = rawoff[r * 17 + dl + 1] - g0;
            int cb0 = c * 16;
            int lo = max(b0 - cb0, 0), hi = min(b1 - cb0, m);
            for (int p = lo; p < hi; p++) {
                short8 w = Raw8[buf * 80 + p * 5 + half];
                #pragma unroll
                for (int k = 0; k < 8; k++) s[k] += bf2f((unsigned short)w[k]);
            }
        }
        if (lastofrel) {
            // A-fragment IS the reduce output: cvt and MFMA directly
            short8 a;
            #pragma unroll
            for (int k = 0; k < 8; k++) a[k] = (short)f2bf(s[k]);
            const short8* Wg8 = (const short8*)W1b + r * 2048 + wv * 8 * 64;
            #pragma unroll
            for (int cbt = 0; cbt < 8; cbt++) {
                short8 b = Wg8[cbt * 64 + lane];
                acc[cbt] = __builtin_amdgcn_mfma_f32_16x16x32_bf16(a, b, acc[cbt], 0, 0, 0);
            }
            #pragma unroll
            for (int k = 0; k < 8; k++) s[k] = 0.f;
        }
        v = vN; m = mN; buf ^= 1;
    }

    // ---- merge K-partials: LDS atomicAdd into zeroed agg ----
    __syncthreads();
    #pragma unroll
    for (int cbt = 0; cbt < 8; cbt++) {
        #pragma unroll
        for (int reg = 0; reg < 4; reg++) {
            atomicAdd(&aggf[(half * 4 + reg) * D + cbt * 16 + dl], acc[cbt][reg]);
        }
    }
    __syncthreads();
    // bias + relu -> bf16 A-tile (aliases dead wave slices)
    unsigned short* Af = (unsigned short*)slices;
    for (int i = t; i < 2048; i += 256) {
        int row = i >> 7, col = i & 127;
        Af[row * 136 + col] = f2bf(fmaxf(aggf[i] + bias1[col], 0.f));
    }
    __syncthreads();
    // epilogue GEMM: out16x64 = Af @ lin_w ; wave wv does out-col tile nt=wv
    f32x4 ao = (f32x4){0.f, 0.f, 0.f, 0.f};
    #pragma unroll
    for (int kc = 0; kc < 4; kc++) {
        short8 a = *(const short8*)(Af + dl * 136 + kc * 32 + half * 8);
        short8 b = *((const short8*)linWb + (kc * 4 + wv) * 64 + lane);
        ao = __builtin_amdgcn_mfma_f32_16x16x32_bf16(a, b, ao, 0, 0, 0);
    }
    float lb = lin_b[wv * 16 + dl];
    #pragma unroll
    for (int reg = 0; reg < 4; reg++) {
        out[(st * 16 + half * 4 + reg) * DO + wv * 16 + dl] = ao[reg] + lb;
    }
}

extern "C" void kernel_launch(void* const* d_in, const int* in_sizes, int n_in,
                              void* d_out, int out_size, void* d_ws, size_t ws_size,
                              hipStream_t stream) {
    const int*   src    = (const int*)d_in[0];
    const int*   dst    = (const int*)d_in[1];
    const int*   et     = (const int*)d_in[2];
    const float* basis0 = (const float*)d_in[4];
    const float* wcomp0 = (const float*)d_in[5];
    const float* bias0  = (const float*)d_in[6];
    const float* basis1 = (const float*)d_in[7];
    const float* wcomp1 = (const float*)d_in[8];
    const float* bias1  = (const float*)d_in[9];
    const float* lin_w  = (const float*)d_in[10];
    const float* lin_b  = (const float*)d_in[11];
    float* out = (float*)d_out;

    char* ws = (char*)d_ws;
    int*            cnt2  = (int*)           (ws + 0);
    int*            bsum  = (int*)           (ws + 4003840);
    int*            boff2 = (int*)           (ws + 4007808);
    int*            gcur2 = (int*)           (ws + 8011712);
    float*          W0    = (float*)         (ws + 12015616);
    unsigned short* W1b   = (unsigned short*)(ws + 12025856);
    unsigned short* h1b   = (unsigned short*)(ws + 12681216);
    int*            epack = (int*)           (ws + 25481216);
    unsigned short* linWb = (unsigned short*)(ws + 28681216);

    hipMemsetAsync(ws, 0, 4003840, stream);   // zero cnt2

    k_weights<<<160, 256, 0, stream>>>(basis0, wcomp0, basis1, wcomp1, lin_w,
                                       W0, W1b, linWb);
    k_hist<<<782, 1024, 0, stream>>>(dst, et, cnt2);
    k_scan1<<<NSB, 1024, 0, stream>>>(cnt2, boff2, bsum);
    k_scan2<<<1, 1024, 0, stream>>>(bsum);
    k_scan3<<<NSB, 1024, 0, stream>>>(boff2, bsum, gcur2);
    k_h1<<<NT, 512, 0, stream>>>(cnt2, W0, bias0, h1b);
    k_scatter<<<782, 1024, 0, stream>>>(src, dst, et, gcur2, epack);
    k_mega<<<NST, 256, 0, stream>>>(epack, boff2, h1b, W1b, linWb,
                                    bias1, lin_b, out);
}

// Round 13
// 208.421 us; speedup vs baseline: 1.9304x; 1.9304x over previous
//
#include <hip/hip_runtime.h>
#include <hip/hip_bf16.h>

#define NN 50000      // nodes
#define NE 800000     // edges
#define NR 20         // relations
#define NB 8          // bases
#define D  128        // hidden dim
#define DO 64         // output dim
#define NT 782        // ceil(NN/64) dst tiles
#define NBKT (NT*1280) // (tile, rel, dl) buckets = 1,000,960
#define NSB 978       // ceil(NBKT/1024)

typedef __attribute__((ext_vector_type(8))) short short8;
typedef __attribute__((ext_vector_type(4))) float f32x4;

__device__ inline unsigned short f2bf(float f) {
    __hip_bfloat16 h = __float2bfloat16(f);
    return *reinterpret_cast<unsigned short*>(&h);
}
__device__ inline float bf2f(unsigned short u) {
    unsigned x = ((unsigned)u) << 16;
    float f;
    __builtin_memcpy(&f, &x, 4);
    return f;
}

// ---------------------------------------------------------------------------
// ws layout (bytes):
//   [0        ..  4,003,840) cnt2  | [4,003,840.. 4,007,752) bsum
//   [4,007,808..  8,011,652) boff2 | [8,011,712..12,015,552) gcur2
//   [12,015,616..12,025,856) W0    | [12,025,856..12,681,216) W1b
//   [12,681,216..25,481,216) h1b   | [25,481,216..28,681,216) epack
//   [28,681,216..28,697,600) linWb (lin_w in B-fragment order, bf16)
// ---------------------------------------------------------------------------

__global__ __launch_bounds__(256) void k_weights(
        const float* __restrict__ basis0, const float* __restrict__ wcomp0,
        const float* __restrict__ basis1, const float* __restrict__ wcomp1,
        const float* __restrict__ lin_w,
        float* __restrict__ W0, unsigned short* __restrict__ W1b,
        unsigned short* __restrict__ linWb) {
    int idx = blockIdx.x * 256 + threadIdx.x;   // 0..40959
    if (idx < NR * D) {
        int r = idx / D, o = idx % D;
        float a = 0.f;
        #pragma unroll
        for (int b = 0; b < NB; b++) a += wcomp0[r * NB + b] * basis0[b * D + o];
        W0[idx] = a;
    }
    if (idx < 16 * 64) {
        int lane = idx & 63, fr = idx >> 6;
        int kc = fr >> 2, nt = fr & 3;
        int i0 = kc * 32 + (lane >> 4) * 8;
        int o = nt * 16 + (lane & 15);
        short8 v;
        #pragma unroll
        for (int e = 0; e < 8; e++) v[e] = (short)f2bf(lin_w[(i0 + e) * DO + o]);
        *((short8*)linWb + idx) = v;
    }
    if (idx < NR * 4 * 8 * 64) {
        int lane = idx & 63;
        int cb   = (idx >> 6) & 7;
        int kc   = (idx >> 9) & 3;
        int rel  = idx >> 11;
        float wc[NB];
        #pragma unroll
        for (int b = 0; b < NB; b++) wc[b] = wcomp1[rel * NB + b];
        int o  = cb * 16 + (lane & 15);
        int i0 = kc * 32 + (lane >> 4) * 8;
        short8 v;
        #pragma unroll
        for (int e = 0; e < 8; e++) {
            int i = i0 + e;
            float a = 0.f;
            #pragma unroll
            for (int b = 0; b < NB; b++) a += wc[b] * basis1[(b * D + i) * D + o];
            v[e] = (short)f2bf(a);
        }
        *((short8*)W1b + idx) = v;
    }
}

__global__ __launch_bounds__(1024) void k_hist(
        const int* __restrict__ dst, const int* __restrict__ et,
        int* __restrict__ cnt2) {
    int i = blockIdx.x * 1024 + threadIdx.x;
    if (i < NE) {
        int d = dst[i];
        int key = (d >> 6) * 1280 + et[i] * 64 + (d & 63);
        atomicAdd(&cnt2[key], 1);
    }
}

__global__ __launch_bounds__(1024) void k_scan1(const int* __restrict__ cnt2,
                                                int* __restrict__ boff2,
                                                int* __restrict__ bsum) {
    __shared__ int ws[16];
    int t = threadIdx.x, lane = t & 63, wv = t >> 6;
    int i = blockIdx.x * 1024 + t;
    int v = (i < NBKT) ? cnt2[i] : 0;
    int inc = v;
    for (int dd = 1; dd < 64; dd <<= 1) {
        int u = __shfl_up(inc, dd);
        if (lane >= dd) inc += u;
    }
    if (lane == 63) ws[wv] = inc;
    __syncthreads();
    if (t == 0) { int a = 0; for (int j = 0; j < 16; j++) { int x = ws[j]; ws[j] = a; a += x; } }
    __syncthreads();
    int ex = ws[wv] + inc - v;
    if (i < NBKT) boff2[i] = ex;
    if (t == 1023) bsum[blockIdx.x] = ex + v;
}

__global__ __launch_bounds__(1024) void k_scan2(int* __restrict__ bsum) {
    __shared__ int ws[16];
    int t = threadIdx.x, lane = t & 63, wv = t >> 6;
    int v = (t < NSB) ? bsum[t] : 0;
    int inc = v;
    for (int dd = 1; dd < 64; dd <<= 1) {
        int u = __shfl_up(inc, dd);
        if (lane >= dd) inc += u;
    }
    if (lane == 63) ws[wv] = inc;
    __syncthreads();
    if (t == 0) { int a = 0; for (int j = 0; j < 16; j++) { int x = ws[j]; ws[j] = a; a += x; } }
    __syncthreads();
    if (t < NSB) bsum[t] = ws[wv] + inc - v;
}

__global__ __launch_bounds__(1024) void k_scan3(int* __restrict__ boff2,
                                                const int* __restrict__ bsum,
                                                int* __restrict__ gcur2) {
    int i = blockIdx.x * 1024 + threadIdx.x;
    if (i < NBKT) {
        int f = boff2[i] + bsum[i >> 10];
        boff2[i] = f;
        gcur2[i] = f;
    }
    if (i == 0) boff2[NBKT] = NE;
}

__global__ __launch_bounds__(1024) void k_scatter(
        const int* __restrict__ src, const int* __restrict__ dst,
        const int* __restrict__ et, int* __restrict__ gcur2,
        int* __restrict__ epack) {
    int i = blockIdx.x * 1024 + threadIdx.x;
    if (i < NE) {
        int d = dst[i];
        int key = (d >> 6) * 1280 + et[i] * 64 + (d & 63);
        int pos = atomicAdd(&gcur2[key], 1);
        epack[pos] = src[i];
    }
}

__global__ __launch_bounds__(512) void k_h1(const int* __restrict__ cnt2,
                                            const float* __restrict__ W0,
                                            const float* __restrict__ bias0,
                                            unsigned short* __restrict__ h1b) {
    __shared__ float cs[NR * 64];
    __shared__ float w0s[NR * D];
    int t = threadIdx.x, tile = blockIdx.x;
    for (int i = t; i < NR * 64; i += 512) cs[i] = (float)cnt2[tile * 1280 + i];
    for (int i = t; i < NR * D; i += 512) w0s[i] = W0[i];
    __syncthreads();
    int nl = t >> 3, cg = t & 7;
    int n = tile * 64 + nl;
    if (n < NN) {
        float a[16];
        #pragma unroll
        for (int j = 0; j < 16; j++) a[j] = bias0[cg * 16 + j];
        for (int r = 0; r < NR; r++) {
            float c = cs[r * 64 + nl];
            #pragma unroll
            for (int j = 0; j < 16; j++) a[j] += c * w0s[r * D + cg * 16 + j];
        }
        short8 o0, o1;
        #pragma unroll
        for (int j = 0; j < 8; j++) {
            o0[j] = (short)f2bf(fmaxf(a[j], 0.f));
            o1[j] = (short)f2bf(fmaxf(a[8 + j], 0.f));
        }
        *((short8*)(h1b + n * D + cg * 16))     = o0;
        *((short8*)(h1b + n * D + cg * 16 + 8)) = o1;
    }
}

// Mega v11: r6's proven 64-dst-tile stage/reduce/publish body + cb-ownership
// MFMA. 512 thr, 8 waves; wave wv owns output cols wv*16..wv*16+15 for ALL
// 64 rows (acc = 4 rowblocks x f32x4 = 16 VGPR) -> per rel only 4 B-loads
// per wave, EACH REUSED 4x, issued at rel-top so L2 latency hides under the
// gather+reduce. No K-split -> no merge phase at all. 2 barriers per rel.
// Epilogue: bias+relu -> bf16 Af (aliases Raw), linear 128->64 via MFMA.
__global__ __launch_bounds__(512, 2) void k_mega(
        const int* __restrict__ epack, const int* __restrict__ boff2,
        const unsigned short* __restrict__ h1b,
        const unsigned short* __restrict__ W1b,
        const unsigned short* __restrict__ linWb,
        const float* __restrict__ bias1, const float* __restrict__ lin_b,
        float* __restrict__ out) {
    __shared__ __align__(16) char lds[17408 + 16384];  // Raw 64x17s8 | Sl 64x16s8
    __shared__ int ooff[1281];

    short8* Raw8 = (short8*)lds;
    short8* Sl8  = (short8*)(lds + 17408);

    int t = threadIdx.x, tile = blockIdx.x;
    int wv = t >> 6, lane = t & 63;
    int le = t >> 3, lp = t & 7;             // stage role: edge row, 16B pair
    int dl = t >> 3, cg = t & 7;             // reduce role: dst-local, col-group
    int row = lane & 15, gg = lane >> 4;     // mfma role

    for (int i = t; i < 1281; i += 512) ooff[i] = boff2[tile * 1280 + i];
    __syncthreads();

    f32x4 acc[4];
    #pragma unroll
    for (int j = 0; j < 4; j++) acc[j] = (f32x4){0.f, 0.f, 0.f, 0.f};

    for (int r = 0; r < NR; r++) {
        int rbase = ooff[r * 64];
        int cnt = ooff[r * 64 + 64] - rbase;     // block-uniform
        if (cnt == 0) continue;

        // B prefetch: wave's cb column-block, 4 kc frags (reused 4x each).
        // Issued first -> ~250cy L2 latency hides under stage+reduce.
        const short8* Wg8 = (const short8*)W1b + r * 2048;
        short8 breg[4];
        #pragma unroll
        for (int kc = 0; kc < 4; kc++) breg[kc] = Wg8[(kc * 8 + wv) * 64 + lane];

        float s[16];
        #pragma unroll
        for (int k = 0; k < 16; k++) s[k] = 0.f;
        int o0 = ooff[r * 64 + dl] - rbase;
        int o1 = ooff[r * 64 + dl + 1] - rbase;
        int nc = (cnt + 63) >> 6;

        for (int c = 0; c < nc; c++) {
            int cb0 = c * 64, m = min(64, cnt - cb0);
            if (c > 0) __syncthreads();          // prev reduce done, Raw reusable
            if (le < m) {
                int node = epack[rbase + cb0 + le];
                const short8* hp = (const short8*)(h1b + (size_t)node * D) + lp * 2;
                Raw8[le * 17 + lp * 2]     = hp[0];
                Raw8[le * 17 + lp * 2 + 1] = hp[1];
            }
            __syncthreads();                     // Raw visible
            int lo = max(o0 - cb0, 0), hi = min(o1 - cb0, m);
            for (int p = lo; p < hi; p++) {
                short8 w0 = Raw8[p * 17 + 2 * cg];
                short8 w1 = Raw8[p * 17 + 2 * cg + 1];
                #pragma unroll
                for (int k = 0; k < 8; k++) {
                    s[k]     += bf2f((unsigned short)w0[k]);
                    s[8 + k] += bf2f((unsigned short)w1[k]);
                }
            }
        }
        // publish swizzled bf16 S-tile
        short8 p0, p1;
        #pragma unroll
        for (int k = 0; k < 8; k++) {
            p0[k] = (short)f2bf(s[k]);
            p1[k] = (short)f2bf(s[8 + k]);
        }
        Sl8[dl * 16 + ((cg * 2)     ^ (dl & 15))] = p0;
        Sl8[dl * 16 + ((cg * 2 + 1) ^ (dl & 15))] = p1;
        __syncthreads();                         // Sl visible (all reduces done)
        // MFMA: 4 rowblocks x 4 kc, B from registers (reuse 4x)
        #pragma unroll
        for (int rb = 0; rb < 4; rb++) {
            int arow = rb * 16 + row;
            #pragma unroll
            for (int kc = 0; kc < 4; kc++) {
                short8 a = Sl8[arow * 16 + ((kc * 4 + gg) ^ (arow & 15))];
                acc[rb] = __builtin_amdgcn_mfma_f32_16x16x32_bf16(a, breg[kc], acc[rb], 0, 0, 0);
            }
        }
        // no barrier needed: next rel's stage hits Raw (not Sl); next publish
        // is ordered after the next stage-barrier, which waits for these MFMAs.
    }

    __syncthreads();                             // last-rel Sl reads done
    // epilogue part 1: bias + relu -> bf16 Af[64][136] (aliases Raw region)
    unsigned short* Af = (unsigned short*)lds;
    #pragma unroll
    for (int rb = 0; rb < 4; rb++) {
        #pragma unroll
        for (int reg = 0; reg < 4; reg++) {
            int rr = rb * 16 + gg * 4 + reg;
            int col = wv * 16 + row;
            Af[rr * 136 + col] = f2bf(fmaxf(acc[rb][reg] + bias1[col], 0.f));
        }
    }
    __syncthreads();
    // epilogue part 2: out[64x64] = Af @ lin_w + lin_b via MFMA
    // wave wv: rowblock rb = wv&3, col-tile pair nt = (wv>>2)*2 .. +1
    {
        int rb = wv & 3;
        int nt0 = (wv >> 2) * 2, nt1 = nt0 + 1;
        f32x4 ao0 = (f32x4){0.f, 0.f, 0.f, 0.f};
        f32x4 ao1 = (f32x4){0.f, 0.f, 0.f, 0.f};
        #pragma unroll
        for (int kc = 0; kc < 4; kc++) {
            short8 a = *(const short8*)(Af + (rb * 16 + row) * 136 + kc * 32 + gg * 8);
            short8 b0 = *((const short8*)linWb + (kc * 4 + nt0) * 64 + lane);
            short8 b1 = *((const short8*)linWb + (kc * 4 + nt1) * 64 + lane);
            ao0 = __builtin_amdgcn_mfma_f32_16x16x32_bf16(a, b0, ao0, 0, 0, 0);
            ao1 = __builtin_amdgcn_mfma_f32_16x16x32_bf16(a, b1, ao1, 0, 0, 0);
        }
        float lb0 = lin_b[nt0 * 16 + row];
        float lb1 = lin_b[nt1 * 16 + row];
        #pragma unroll
        for (int reg = 0; reg < 4; reg++) {
            int d = tile * 64 + rb * 16 + gg * 4 + reg;
            if (d < NN) {
                out[d * DO + nt0 * 16 + row] = ao0[reg] + lb0;
                out[d * DO + nt1 * 16 + row] = ao1[reg] + lb1;
            }
        }
    }
}

extern "C" void kernel_launch(void* const* d_in, const int* in_sizes, int n_in,
                              void* d_out, int out_size, void* d_ws, size_t ws_size,
                              hipStream_t stream) {
    const int*   src    = (const int*)d_in[0];
    const int*   dst    = (const int*)d_in[1];
    const int*   et     = (const int*)d_in[2];
    const float* basis0 = (const float*)d_in[4];
    const float* wcomp0 = (const float*)d_in[5];
    const float* bias0  = (const float*)d_in[6];
    const float* basis1 = (const float*)d_in[7];
    const float* wcomp1 = (const float*)d_in[8];
    const float* bias1  = (const float*)d_in[9];
    const float* lin_w  = (const float*)d_in[10];
    const float* lin_b  = (const float*)d_in[11];
    float* out = (float*)d_out;

    char* ws = (char*)d_ws;
    int*            cnt2  = (int*)           (ws + 0);
    int*            bsum  = (int*)           (ws + 4003840);
    int*            boff2 = (int*)           (ws + 4007808);
    int*            gcur2 = (int*)           (ws + 8011712);
    float*          W0    = (float*)         (ws + 12015616);
    unsigned short* W1b   = (unsigned short*)(ws + 12025856);
    unsigned short* h1b   = (unsigned short*)(ws + 12681216);
    int*            epack = (int*)           (ws + 25481216);
    unsigned short* linWb = (unsigned short*)(ws + 28681216);

    hipMemsetAsync(ws, 0, 4003840, stream);   // zero cnt2

    k_weights<<<160, 256, 0, stream>>>(basis0, wcomp0, basis1, wcomp1, lin_w,
                                       W0, W1b, linWb);
    k_hist<<<782, 1024, 0, stream>>>(dst, et, cnt2);
    k_scan1<<<NSB, 1024, 0, stream>>>(cnt2, boff2, bsum);
    k_scan2<<<1, 1024, 0, stream>>>(bsum);
    k_scan3<<<NSB, 1024, 0, stream>>>(boff2, bsum, gcur2);
    k_h1<<<NT, 512, 0, stream>>>(cnt2, W0, bias0, h1b);
    k_scatter<<<782, 1024, 0, stream>>>(src, dst, et, gcur2, epack);
    k_mega<<<NT, 512, 0, stream>>>(epack, boff2, h1b, W1b, linWb,
                                   bias1, lin_b, out);
}